// Round 10
// baseline (204.858 us; speedup 1.0000x reference)
//
#include <hip/hip_runtime.h>
#include <math.h>

#define TT 1536
#define CC 1536
#define NH 8
#define KD 64
#define VD 192
#define FD 192

typedef short bf16x8 __attribute__((ext_vector_type(8)));
typedef float f32x4 __attribute__((ext_vector_type(4)));

__device__ inline unsigned short f2bf(float x) {
    unsigned u = __float_as_uint(x);
    u += 0x7FFF + ((u >> 16) & 1);
    return (unsigned short)(u >> 16);
}
__device__ inline float bf2f(unsigned short b) {
    return __uint_as_float(((unsigned)b) << 16);
}
__device__ inline void gload16(const void* g, void* l) {
    __builtin_amdgcn_global_load_lds(
        (const __attribute__((address_space(1))) unsigned int*)g,
        (__attribute__((address_space(3))) unsigned int*)l, 16, 0, 0);
}
// 16B-chunk XOR swizzle within a 64-elem (128B) bf16 row: chunk' = chunk ^ (row&7)
__device__ inline int swzo(int row, int chunk) { return (chunk ^ (row & 7)) << 3; }

template<int N> __device__ inline void vmwait() {
    if constexpr (N == 0)      asm volatile("s_waitcnt vmcnt(0)" ::: "memory");
    else if constexpr (N == 4) asm volatile("s_waitcnt vmcnt(4)" ::: "memory");
    else if constexpr (N == 6) asm volatile("s_waitcnt vmcnt(6)" ::: "memory");
    else                       asm volatile("s_waitcnt vmcnt(8)" ::: "memory");
}

// ---------------- wave-per-row LayerNorm helper (f32 -> bf16) ----------------
__device__ inline void ln_row(const float* __restrict__ x,
                              const float* __restrict__ g,
                              const float* __restrict__ b,
                              unsigned short* __restrict__ out,
                              int row, int lane)
{
    const float* xr = x + (size_t)row * CC;
    unsigned short* orow = out + (size_t)row * CC;

    float4 V[6];
    float s = 0.f, ss = 0.f;
#pragma unroll
    for (int c = 0; c < 6; c++) {
        V[c] = *reinterpret_cast<const float4*>(&xr[c * 256 + lane * 4]);
        s  += V[c].x + V[c].y + V[c].z + V[c].w;
        ss += V[c].x * V[c].x + V[c].y * V[c].y + V[c].z * V[c].z + V[c].w * V[c].w;
    }
#pragma unroll
    for (int off = 32; off; off >>= 1) {
        s  += __shfl_xor(s, off);
        ss += __shfl_xor(ss, off);
    }
    float mean = s * (1.f / CC);
    float var  = ss * (1.f / CC) - mean * mean;
    float rstd = rsqrtf(fmaxf(var, 0.f) + 1e-3f);
#pragma unroll
    for (int c = 0; c < 6; c++) {
        float4 G = *reinterpret_cast<const float4*>(&g[c * 256 + lane * 4]);
        float4 B = *reinterpret_cast<const float4*>(&b[c * 256 + lane * 4]);
        ushort4 pk;
        pk.x = f2bf((V[c].x - mean) * rstd * G.x + B.x);
        pk.y = f2bf((V[c].y - mean) * rstd * G.y + B.y);
        pk.z = f2bf((V[c].z - mean) * rstd * G.z + B.z);
        pk.w = f2bf((V[c].w - mean) * rstd * G.w + B.w);
        *reinterpret_cast<ushort4*>(&orow[c * 256 + lane * 4]) = pk;
    }
}

// standalone ln (4 rows per block, 1 wave per row)
__global__ __launch_bounds__(256)
void ln_kernel(const float* __restrict__ x, const float* __restrict__ g,
               const float* __restrict__ b, unsigned short* __restrict__ out)
{
    int wid = threadIdx.x >> 6, lane = threadIdx.x & 63;
    ln_row(x, g, b, out, blockIdx.x * 4 + wid, lane);
}

// ---------------- merged prep: weight convert (7 mats) + ln1 + pos -----------
struct WCD { const float* W; unsigned short* Wt; int Kw, Nw, t0; };
struct WCP { WCD e[7]; };
#define WCONV_BLKS 15456
#define LN1_BLKS   384
#define POS_BLKS   (2 * TT - 1)

__global__ __launch_bounds__(256)
void prep_all(WCP p, const float* __restrict__ x,
              const float* __restrict__ ln1_g, const float* __restrict__ ln1_b,
              unsigned short* __restrict__ xnb, unsigned short* __restrict__ pos)
{
    int bid = blockIdx.x;
    int tid = threadIdx.x;

    if (bid < WCONV_BLKS) {
        __shared__ float t[32][33];
        int i = 0;
#pragma unroll
        for (int j = 1; j < 7; j++) if (bid >= p.e[j].t0) i = j;
        const float* W = p.e[i].W;
        unsigned short* Wt = p.e[i].Wt;
        int Kw = p.e[i].Kw, Nw = p.e[i].Nw;
        int local = bid - p.e[i].t0;
        int tpx = Nw >> 5;
        int n0 = (local % tpx) * 32, k0 = (local / tpx) * 32;

        int r = tid >> 3, c4 = (tid & 7) * 4;
        float4 v = *reinterpret_cast<const float4*>(&W[(size_t)(k0 + r) * Nw + n0 + c4]);
        t[r][c4 + 0] = v.x; t[r][c4 + 1] = v.y; t[r][c4 + 2] = v.z; t[r][c4 + 3] = v.w;
        __syncthreads();
        ushort4 pk;
        pk.x = f2bf(t[c4 + 0][r]);
        pk.y = f2bf(t[c4 + 1][r]);
        pk.z = f2bf(t[c4 + 2][r]);
        pk.w = f2bf(t[c4 + 3][r]);
        *reinterpret_cast<ushort4*>(&Wt[(size_t)(n0 + r) * Kw + k0 + c4]) = pk;
        return;
    }

    if (bid < WCONV_BLKS + LN1_BLKS) {
        int grp = bid - WCONV_BLKS;
        int wid = tid >> 6, lane = tid & 63;
        ln_row(x, ln1_g, ln1_b, xnb, grp * 4 + wid, lane);
        return;
    }

    // positional features, one l per block
    {
        int l = bid - (WCONV_BLKS + LN1_BLKS);
        float pp = (float)(l - (TT - 1));
        float ap = fabsf(pp);
        float sgn = (pp > 0.f) ? 1.f : ((pp < 0.f) ? -1.f : 0.f);

        __shared__ float gp[32];
        __shared__ float gmax_s;
        if (tid < 32) {
            int j = tid;
            double conc = 4.0 * (double)(j + 1) * (double)(j + 1);
            double rate = (double)(j + 1) / 12.0;
            double log_norm = lgamma(conc) - conc * log(rate);
            double prob;
            if (ap == 0.f) prob = 1e-8;
            else prob = exp((conc - 1.0) * log((double)ap) - rate * (double)ap - log_norm) + 1e-8;
            gp[j] = (float)prob;
        }
        __syncthreads();
        if (tid == 0) {
            float m = gp[0];
            for (int j = 1; j < 32; j++) m = fmaxf(m, gp[j]);
            gmax_s = m;
        }
        __syncthreads();
        if (tid < 96) {
            int cls = tid / 32, j = tid % 32;
            float val;
            if (cls == 0) {
                double step = (10.584962500721156 - 3.0) / 31.0;
                double hl = exp2(3.0 + j * step);
                val = (float)exp(-(double)ap * 0.6931471805599453 / hl);
            } else if (cls == 1) {
                float width = exp2f((float)(j + 1)) - 1.f;
                val = (width > ap) ? 1.f : 0.f;
            } else {
                val = gp[j] / gmax_s;
            }
            pos[(size_t)l * FD + tid] = f2bf(val);
            pos[(size_t)l * FD + 96 + tid] = f2bf(sgn * val);
        }
    }
}

// ---------------- bf16 MFMA GEMM core, TMxTN tile, 4 waves ----------------
// DEPTH=2: classic double buffer, 2 barriers/K-step.
// DEPTH=3: ring buffer, SINGLE barrier/K-step (stage t+2 after barrier t —
//          safe because barrier t proves all waves finished step t-1 reads
//          of the same physical buffer).
// xm: 2 or 4 -> 2D XCD chunking; 0 -> linear XCD swizzle.
// mode 0: f32 out  mode 1: bf16 out  mode 4: fused qkv epilogue
// head_ndiv!=0: A += (n0/head_ndiv)*sA
template<int TM, int TN, int DEPTH>
__device__ void gemm_core(const unsigned short* __restrict__ A,
                          const unsigned short* __restrict__ Bt,
                          void* __restrict__ Cv, unsigned short* __restrict__ C2,
                          unsigned short* __restrict__ C3,
                          int M, int N, int K, int lda, int ldb, int ldc,
                          long sA, long sB, long sC,
                          float alpha, const float* __restrict__ bias,
                          const float* __restrict__ bias2,
                          const float* __restrict__ resid,
                          int mode, int relu, int head_ndiv, int xm,
                          int gx, int gy, int d, int bz)
{
    constexpr int WM = TM / 2, WN = TN / 2;
    constexpr int MF = WM / 16, NF = WN / 16;
    constexpr int LPT = TM / 32 + TN / 32;       // per-thread loads per K-tile
    __shared__ unsigned short lA[DEPTH][TM * 64];
    __shared__ unsigned short lB[DEPTH][TN * 64];

    int tid = threadIdx.x;
    int w = tid >> 6, l = tid & 63;

    int bx, by;
    if (xm) {
        int xn = 8 / xm;
        int cm = gy / xm, cn = gx / xn;
        int xcd = d & 7, local = d >> 3;
        int bxl = local / cm, byl = local % cm;
        by = (xcd / xn) * cm + byl;
        bx = (xcd % xn) * cn + bxl;
    } else {
        int nwg = gx * gy;
        int work = d;
        if ((nwg & 7) == 0) work = (d & 7) * (nwg >> 3) + (d >> 3);
        bx = work % gx;
        by = work / gx;
    }

    int n0 = bx * TN;
    int m0 = by * TM;
    if (head_ndiv) {
        A += (size_t)(n0 / head_ndiv) * sA;
    } else {
        A  += (size_t)bz * sA;
        Bt += (size_t)bz * sB;
    }
    int R0 = (w & 1) * WM, C0 = (w >> 1) * WN;
    int lrow = l >> 3;
    int lsw = ((l & 7) ^ lrow) << 3;       // swizzled source chunk (elements)
    int l15 = l & 15, lg = l >> 4;

    f32x4 acc[MF][NF] = {};

    const int NSTEP = K >> 6;

    auto STAGE = [&](int t, int buf) {
        int k0 = t << 6;
#pragma unroll
        for (int q = 0; q < TM / 32; q++) {
            int r0 = w * (TM / 4) + q * 8;
            gload16(A + (size_t)(m0 + r0 + lrow) * lda + k0 + lsw, &lA[buf][r0 * 64]);
        }
#pragma unroll
        for (int q = 0; q < TN / 32; q++) {
            int r0 = w * (TN / 4) + q * 8;
            gload16(Bt + (size_t)(n0 + r0 + lrow) * ldb + k0 + lsw, &lB[buf][r0 * 64]);
        }
    };

    auto COMPUTE = [&](int cur) {
#pragma unroll
        for (int kk = 0; kk < 2; kk++) {
            int ch = kk * 4 + lg;
            bf16x8 av[MF], bv[NF];
#pragma unroll
            for (int m = 0; m < MF; m++) {
                int row = R0 + m * 16 + l15;
                av[m] = *(const bf16x8*)&lA[cur][row * 64 + swzo(row, ch)];
            }
#pragma unroll
            for (int n = 0; n < NF; n++) {
                int row = C0 + n * 16 + l15;
                bv[n] = *(const bf16x8*)&lB[cur][row * 64 + swzo(row, ch)];
            }
#pragma unroll
            for (int m = 0; m < MF; m++)
#pragma unroll
                for (int n = 0; n < NF; n++)
                    acc[m][n] = __builtin_amdgcn_mfma_f32_16x16x32_bf16(av[m], bv[n], acc[m][n], 0, 0, 0);
        }
    };

    if constexpr (DEPTH == 2) {
        STAGE(0, 0);
        int cur = 0;
        for (int t = 0; t < NSTEP; ++t) {
            if (t + 1 < NSTEP) {
                STAGE(t + 1, cur ^ 1);     // buffer freed by barrier at end of t-1
                vmwait<LPT>();             // tile t complete; t+1 stays in flight
            } else {
                vmwait<0>();
            }
            __builtin_amdgcn_s_barrier();
            __builtin_amdgcn_sched_barrier(0);
            COMPUTE(cur);
            __builtin_amdgcn_s_barrier();  // all waves done reading buf cur
            cur ^= 1;
        }
    } else {
        // depth-3 ring, single barrier per K-step
        STAGE(0, 0);
        if (NSTEP > 1) STAGE(1, 1);
        int cur = 0;
        for (int t = 0; t < NSTEP; ++t) {
            if (t + 1 < NSTEP) vmwait<LPT>();   // buf[cur] landed; t+1 in flight
            else               vmwait<0>();
            __builtin_amdgcn_s_barrier();       // all waves done with step t-1 reads
            __builtin_amdgcn_sched_barrier(0);
            if (t + 2 < NSTEP) {
                int b2 = cur + 2; if (b2 >= 3) b2 -= 3;
                STAGE(t + 2, b2);               // overwrites step t-1's buffer: safe
            }
            COMPUTE(cur);
            cur = (cur == 2) ? 0 : cur + 1;
        }
    }

    int rb = m0 + R0 + lg * 4;
    int cb = n0 + C0 + l15;

    if (mode == 4) {
        unsigned short* qw = (unsigned short*)Cv;
#pragma unroll
        for (int m = 0; m < MF; m++) {
            int rowb = rb + m * 16;
#pragma unroll
            for (int n = 0; n < NF; n++) {
                int col = cb + n * 16;
                if (col < 512) {
#pragma unroll
                    for (int reg = 0; reg < 4; reg++) {
                        int row = rowb + reg;
                        float v = alpha * acc[m][n][reg];
                        qw[(size_t)row * 512 + col] = f2bf(v + bias[col]);
                        C2[(size_t)row * 512 + col] = f2bf(v + bias2[col]);
                    }
                } else if (col < 1024) {
                    unsigned short* kb = C3;
#pragma unroll
                    for (int reg = 0; reg < 4; reg++)
                        kb[(size_t)(rowb + reg) * 512 + col - 512] = f2bf(acc[m][n][reg]);
                } else {
                    unsigned short* vT = (unsigned short*)(void*)(C3 + (size_t)1536 * 512);
                    int vc = col - 1024;
                    ushort4 pk;
                    pk.x = f2bf(acc[m][n][0]);
                    pk.y = f2bf(acc[m][n][1]);
                    pk.z = f2bf(acc[m][n][2]);
                    pk.w = f2bf(acc[m][n][3]);
                    *reinterpret_cast<ushort4*>(&vT[(size_t)vc * 1536 + rowb]) = pk;
                }
            }
        }
        return;
    }

#pragma unroll
    for (int m = 0; m < MF; m++) {
#pragma unroll
        for (int n = 0; n < NF; n++) {
            int col = cb + n * 16;
            if (col >= N) continue;
            float bs = bias ? bias[col] : 0.f;
#pragma unroll
            for (int reg = 0; reg < 4; reg++) {
                int row = rb + m * 16 + reg;
                if (row >= M) continue;
                float v = alpha * acc[m][n][reg] + bs;
                if (resid) v += resid[(size_t)row * ldc + col];
                if (relu)  v = fmaxf(v, 0.f);
                if (mode == 1) {
                    unsigned short* C = (unsigned short*)Cv + (size_t)bz * sC;
                    C[(size_t)row * ldc + col] = f2bf(v);
                } else {
                    float* C = (float*)Cv + (size_t)bz * sC;
                    C[(size_t)row * ldc + col] = v;
                }
            }
        }
    }
}

template<int TM, int TN, int DEPTH = 2>
__global__ __launch_bounds__(256)
void gemm_bf16(const unsigned short* __restrict__ A,
               const unsigned short* __restrict__ Bt,
               void* __restrict__ Cv, unsigned short* __restrict__ C2,
               unsigned short* __restrict__ C3,
               int M, int N, int K, int lda, int ldb, int ldc,
               long sA, long sB, long sC,
               float alpha, const float* __restrict__ bias,
               const float* __restrict__ bias2,
               const float* __restrict__ resid,
               int mode, int relu, int head_ndiv, int xm)
{
    int d = blockIdx.y * gridDim.x + blockIdx.x;
    gemm_core<TM, TN, DEPTH>(A, Bt, Cv, C2, C3, M, N, K, lda, ldb, ldc, sA, sB, sC,
                             alpha, bias, bias2, resid, mode, relu, head_ndiv, xm,
                             gridDim.x, gridDim.y, d, blockIdx.z);
}

// two independent <64,128> GEMMs in one launch (block-range dispatch)
struct GP {
    const unsigned short *A, *Bt;
    void* Cv; unsigned short *C2, *C3;
    int M, N, K, lda, ldb, ldc;
    long sA, sB, sC;
    float alpha;
    const float *bias, *bias2, *resid;
    int mode, relu, head_ndiv, xm, gx, gy;
};

__global__ __launch_bounds__(256)
void gemm_dual128(GP a, GP b, int nblk0)
{
    int bid = blockIdx.x;
    if (bid < nblk0) {
        gemm_core<64, 128, 2>(a.A, a.Bt, a.Cv, a.C2, a.C3, a.M, a.N, a.K,
                              a.lda, a.ldb, a.ldc, a.sA, a.sB, a.sC, a.alpha,
                              a.bias, a.bias2, a.resid, a.mode, a.relu,
                              a.head_ndiv, a.xm, a.gx, a.gy, bid, 0);
    } else {
        gemm_core<64, 128, 2>(b.A, b.Bt, b.Cv, b.C2, b.C3, b.M, b.N, b.K,
                              b.lda, b.ldb, b.ldc, b.sA, b.sB, b.sC, b.alpha,
                              b.bias, b.bias2, b.resid, b.mode, b.relu,
                              b.head_ndiv, b.xm, b.gx, b.gy, bid - nblk0, 0);
    }
}

// ---------------- MFMA logits: content + shifted rel -> bf16 [8,T,T] ----------
// 40 KB LDS (shift buffer aliased over lQw/lQr as bf16) -> 4 blocks/CU
__global__ __launch_bounds__(256)
void logits_mfma(const unsigned short* __restrict__ qw,
                 const unsigned short* __restrict__ qr,
                 const unsigned short* __restrict__ kmat,
                 const unsigned short* __restrict__ rk,
                 unsigned short* __restrict__ out)
{
    __shared__ unsigned short pool[3 * 64 * 64 + 128 * 64];
    unsigned short* lQw = pool;
    unsigned short* lQr = pool + 64 * 64;
    unsigned short* lK  = pool + 2 * 64 * 64;
    unsigned short* lR  = pool + 3 * 64 * 64;
    unsigned short* lC2 = pool;              // alias lQw+lQr: [64][128] bf16

    int j0 = blockIdx.x * 64;
    int i0 = blockIdx.y * 64;
    int h  = blockIdx.z;
    int tid = threadIdx.x;
    int w = tid >> 6, l = tid & 63;
    int lrow = l >> 3;
    int lsw = ((l & 7) ^ lrow) << 3;
    int l15 = l & 15, lg = l >> 4;
    int obase = j0 - i0 + 1472;

#pragma unroll
    for (int q = 0; q < 2; q++) {
        int r0 = w * 16 + q * 8;
        gload16(qw   + (size_t)(i0 + r0 + lrow) * (NH * KD) + h * KD + lsw, &lQw[r0 * 64]);
        gload16(qr   + (size_t)(i0 + r0 + lrow) * (NH * KD) + h * KD + lsw, &lQr[r0 * 64]);
        gload16(kmat + (size_t)(j0 + r0 + lrow) * (NH * KD) + h * KD + lsw, &lK [r0 * 64]);
    }
#pragma unroll
    for (int q = 0; q < 4; q++) {
        int r0 = w * 32 + q * 8;
        gload16(rk + (size_t)(obase + r0 + lrow) * (NH * KD) + h * KD + lsw, &lR[r0 * 64]);
    }
    __syncthreads();

    f32x4 acc1[4] = {};
    f32x4 acc2[8] = {};
#pragma unroll
    for (int kk = 0; kk < 2; kk++) {
        int ch = kk * 4 + lg;
        int qrow = 16 * w + l15;
        bf16x8 av  = *(const bf16x8*)&lQw[qrow * 64 + swzo(qrow, ch)];
        bf16x8 arv = *(const bf16x8*)&lQr[qrow * 64 + swzo(qrow, ch)];
#pragma unroll
        for (int n = 0; n < 4; n++) {
            int row = n * 16 + l15;
            bf16x8 bv = *(const bf16x8*)&lK[row * 64 + swzo(row, ch)];
            acc1[n] = __builtin_amdgcn_mfma_f32_16x16x32_bf16(av, bv, acc1[n], 0, 0, 0);
        }
#pragma unroll
        for (int n = 0; n < 8; n++) {
            int row = n * 16 + l15;
            bf16x8 rv = *(const bf16x8*)&lR[row * 64 + swzo(row, ch)];
            acc2[n] = __builtin_amdgcn_mfma_f32_16x16x32_bf16(arv, rv, acc2[n], 0, 0, 0);
        }
    }
    __syncthreads();          // all reads of lQw/lQr done before aliased writes

#pragma unroll
    for (int n = 0; n < 8; n++)
#pragma unroll
        for (int reg = 0; reg < 4; reg++)
            lC2[(16 * w + lg * 4 + reg) * 128 + n * 16 + l15] = f2bf(acc2[n][reg]);
    __syncthreads();

#pragma unroll
    for (int n = 0; n < 4; n++) {
#pragma unroll
        for (int reg = 0; reg < 4; reg++) {
            int u = 16 * w + lg * 4 + reg;
            int v = n * 16 + l15;
            float val = acc1[n][reg] + bf2f(lC2[u * 128 + 63 + v - u]);
            out[((size_t)h * TT + i0 + u) * TT + j0 + v] = f2bf(val);
        }
    }
}

// ---------------- Row softmax bf16 in-place, 1 wave per row ----------------
__global__ __launch_bounds__(256)
void softmax_bf16(unsigned short* __restrict__ P)
{
    int wid = threadIdx.x >> 6, lane = threadIdx.x & 63;
    size_t r = (size_t)blockIdx.x * 4 + wid;
    unsigned* row = (unsigned*)(P + r * TT);

    uint4 U[3];
    float v[24];
    float m = -1e30f;
#pragma unroll
    for (int c = 0; c < 3; c++) {
        U[c] = *reinterpret_cast<const uint4*>(&row[c * 256 + lane * 4]);
        const unsigned* pd = (const unsigned*)&U[c];
#pragma unroll
        for (int d = 0; d < 4; d++) {
            float lo = bf2f((unsigned short)(pd[d] & 0xFFFF));
            float hi = bf2f((unsigned short)(pd[d] >> 16));
            v[c * 8 + 2 * d]     = lo;
            v[c * 8 + 2 * d + 1] = hi;
            m = fmaxf(m, fmaxf(lo, hi));
        }
    }
#pragma unroll
    for (int off = 32; off; off >>= 1) m = fmaxf(m, __shfl_xor(m, off));
    float s = 0.f;
#pragma unroll
    for (int i = 0; i < 24; i++) { v[i] = __expf(v[i] - m); s += v[i]; }
#pragma unroll
    for (int off = 32; off; off >>= 1) s += __shfl_xor(s, off);
    float inv = 1.f / s;
#pragma unroll
    for (int c = 0; c < 3; c++) {
        unsigned* pd = (unsigned*)&U[c];
#pragma unroll
        for (int d = 0; d < 4; d++)
            pd[d] = (unsigned)f2bf(v[c * 8 + 2 * d] * inv)
                  | ((unsigned)f2bf(v[c * 8 + 2 * d + 1] * inv) << 16);
        *reinterpret_cast<uint4*>(&row[c * 256 + lane * 4]) = U[c];
    }
}

// ---------------- launcher ----------------
extern "C" void kernel_launch(void* const* d_in, const int* in_sizes, int n_in,
                              void* d_out, int out_size, void* d_ws, size_t ws_size,
                              hipStream_t stream)
{
    const float* x     = (const float*)d_in[0];
    const float* ln1_g = (const float*)d_in[1];
    const float* ln1_b = (const float*)d_in[2];
    const float* ln2_g = (const float*)d_in[3];
    const float* ln2_b = (const float*)d_in[4];
    const float* Wq    = (const float*)d_in[5];
    const float* Wk    = (const float*)d_in[6];
    const float* Wv    = (const float*)d_in[7];
    const float* Wr    = (const float*)d_in[8];
    const float* Wo    = (const float*)d_in[9];
    const float* bo    = (const float*)d_in[10];
    const float* rwb   = (const float*)d_in[11];
    const float* rrb   = (const float*)d_in[12];
    const float* W1    = (const float*)d_in[13];
    const float* b1    = (const float*)d_in[14];
    const float* W2    = (const float*)d_in[15];
    const float* b2    = (const float*)d_in[16];
    float* out = (float*)d_out;

    char* w8 = (char*)d_ws;
    unsigned short* xnb  = (unsigned short*)(w8 + 0);         // [1536][1536]
    unsigned short* qwb  = (unsigned short*)(w8 + 4718592);   // [1536][512]
    unsigned short* qrb  = (unsigned short*)(w8 + 6291456);   // [1536][512]
    unsigned short* kbb  = (unsigned short*)(w8 + 7864320);   // [1536][512]
    unsigned short* vTb  = (unsigned short*)(w8 + 9437184);   // [1536][1536] (= kbb + 1536*512)
    unsigned short* posb = (unsigned short*)(w8 + 14155776);  // [3072][192]
    unsigned short* rkb  = (unsigned short*)(w8 + 15335424);  // [3072][512]
    unsigned short* Pb   = (unsigned short*)(w8 + 18481152);  // [8][1536][1536]
    unsigned short* ob   = (unsigned short*)(w8 + 56229888);  // [1536][1536]
    float*          yb   = (float*)        (w8 + 60948480);   // [1536][1536] f32
    unsigned short* WqkvT= (unsigned short*)(w8 + 70385664);  // [2560][1536]
    unsigned short* WrT  = (unsigned short*)(w8 + 78249984);  // [512][192]
    unsigned short* WoT  = (unsigned short*)(w8 + 78446592);  // [1536][1536]
    unsigned short* W1T  = (unsigned short*)(w8 + 83165184);  // [3072][1536]
    unsigned short* W2T  = (unsigned short*)(w8 + 92602368);  // [1536][3072]
    unsigned short* h1b  = Pb;    // reuse after AV
    unsigned short* ynb  = xnb;   // reuse after QKV

    // merged prep: weight conversions (bf16, transposed) + ln1 + pos
    WCP wp;
    wp.e[0] = { Wq, WqkvT,                       1536, 512,      0 };
    wp.e[1] = { Wk, WqkvT + (size_t)512 * 1536,  1536, 512,    768 };
    wp.e[2] = { Wv, WqkvT + (size_t)1024 * 1536, 1536, 1536,  1536 };
    wp.e[3] = { Wr, WrT,                          192, 512,   3840 };
    wp.e[4] = { Wo, WoT,                         1536, 1536,  3936 };
    wp.e[5] = { W1, W1T,                         1536, 3072,  6240 };
    wp.e[6] = { W2, W2T,                         3072, 1536, 10848 };
    prep_all<<<WCONV_BLKS + LN1_BLKS + POS_BLKS, 256, 0, stream>>>(
        wp, x, ln1_g, ln1_b, xnb, posb);

    // merged launch: fused qkv (480 blocks, 2D XCD chunks) + rk (192 blocks)
    GP ga = { xnb, WqkvT, qwb, qrb, kbb,
              1536, 2560, 1536, 1536, 1536, 0,
              0, 0, 0,
              0.125f, rwb, rrb, nullptr,
              4, 0, 0, 2, 20, 24 };
    GP gb = { posb, WrT, rkb, nullptr, nullptr,
              3071, 512, 192, 192, 192, 512,
              0, 0, 0,
              1.f, nullptr, nullptr, nullptr,
              1, 0, 0, 2, 4, 48 };
    gemm_dual128<<<672, 256, 0, stream>>>(ga, gb, 480);

    // logits + softmax (in place, bf16)
    logits_mfma<<<dim3(24, 24, 8), 256, 0, stream>>>(qwb, qrb, kbb, rkb, Pb);
    softmax_bf16<<<NH * TT / 4, 256, 0, stream>>>(Pb);

    // o = P @ V : 64x64 depth-3 single-barrier (576 blocks), head from n0/192
    gemm_bf16<64, 64, 3><<<dim3(24, 24, 1), 256, 0, stream>>>(Pb, vTb, ob, nullptr, nullptr,
        1536, 1536, 1536, 1536, 1536, 1536, (long)TT * TT, 0, 0,
        1.f, nullptr, nullptr, nullptr, 1, 0, VD, 2);

    // y = o @ Wo + bo + x   (f32) : 64x64 depth-3 single-barrier (576 blocks)
    gemm_bf16<64, 64, 3><<<dim3(24, 24, 1), 256, 0, stream>>>(ob, WoT, yb, nullptr, nullptr,
        1536, 1536, 1536, 1536, 1536, 1536, 0, 0, 0,
        1.f, bo, nullptr, x, 0, 0, 0, 2);

    ln_kernel<<<TT / 4, 256, 0, stream>>>(yb, ln2_g, ln2_b, ynb);

    // h1 = relu(yn @ W1 + b1) bf16 : 64x128 depth-2 (576 blocks)
    gemm_bf16<64, 128, 2><<<dim3(24, 24, 1), 256, 0, stream>>>(ynb, W1T, h1b, nullptr, nullptr,
        1536, 3072, 1536, 1536, 1536, 3072, 0, 0, 0,
        1.f, b1, nullptr, nullptr, 1, 1, 0, 2);

    // out = y + h1 @ W2 + b2   (f32) : 64x64 depth-3 single-barrier, XM=4
    gemm_bf16<64, 64, 3><<<dim3(24, 24, 1), 256, 0, stream>>>(h1b, W2T, out, nullptr, nullptr,
        1536, 1536, 3072, 3072, 3072, 1536, 0, 0, 0,
        1.f, b2, nullptr, yb, 0, 0, 0, 4);
}

// Round 11
// 202.476 us; speedup vs baseline: 1.0118x; 1.0118x over previous
//
#include <hip/hip_runtime.h>
#include <math.h>

#define TT 1536
#define CC 1536
#define NH 8
#define KD 64
#define VD 192
#define FD 192

typedef short bf16x8 __attribute__((ext_vector_type(8)));
typedef float f32x4 __attribute__((ext_vector_type(4)));

__device__ inline unsigned short f2bf(float x) {
    unsigned u = __float_as_uint(x);
    u += 0x7FFF + ((u >> 16) & 1);
    return (unsigned short)(u >> 16);
}
__device__ inline float bf2f(unsigned short b) {
    return __uint_as_float(((unsigned)b) << 16);
}
__device__ inline void gload16(const void* g, void* l) {
    __builtin_amdgcn_global_load_lds(
        (const __attribute__((address_space(1))) unsigned int*)g,
        (__attribute__((address_space(3))) unsigned int*)l, 16, 0, 0);
}
// 16B-chunk XOR swizzle within a 64-elem (128B) bf16 row: chunk' = chunk ^ (row&7)
__device__ inline int swzo(int row, int chunk) { return (chunk ^ (row & 7)) << 3; }

template<int N> __device__ inline void vmwait() {
    if constexpr (N == 0)      asm volatile("s_waitcnt vmcnt(0)" ::: "memory");
    else if constexpr (N == 4) asm volatile("s_waitcnt vmcnt(4)" ::: "memory");
    else if constexpr (N == 6) asm volatile("s_waitcnt vmcnt(6)" ::: "memory");
    else                       asm volatile("s_waitcnt vmcnt(8)" ::: "memory");
}

// ---------------- wave-per-row LayerNorm helper (f32 -> bf16) ----------------
__device__ inline void ln_row(const float* __restrict__ x,
                              const float* __restrict__ g,
                              const float* __restrict__ b,
                              unsigned short* __restrict__ out,
                              int row, int lane)
{
    const float* xr = x + (size_t)row * CC;
    unsigned short* orow = out + (size_t)row * CC;

    float4 V[6];
    float s = 0.f, ss = 0.f;
#pragma unroll
    for (int c = 0; c < 6; c++) {
        V[c] = *reinterpret_cast<const float4*>(&xr[c * 256 + lane * 4]);
        s  += V[c].x + V[c].y + V[c].z + V[c].w;
        ss += V[c].x * V[c].x + V[c].y * V[c].y + V[c].z * V[c].z + V[c].w * V[c].w;
    }
#pragma unroll
    for (int off = 32; off; off >>= 1) {
        s  += __shfl_xor(s, off);
        ss += __shfl_xor(ss, off);
    }
    float mean = s * (1.f / CC);
    float var  = ss * (1.f / CC) - mean * mean;
    float rstd = rsqrtf(fmaxf(var, 0.f) + 1e-3f);
#pragma unroll
    for (int c = 0; c < 6; c++) {
        float4 G = *reinterpret_cast<const float4*>(&g[c * 256 + lane * 4]);
        float4 B = *reinterpret_cast<const float4*>(&b[c * 256 + lane * 4]);
        ushort4 pk;
        pk.x = f2bf((V[c].x - mean) * rstd * G.x + B.x);
        pk.y = f2bf((V[c].y - mean) * rstd * G.y + B.y);
        pk.z = f2bf((V[c].z - mean) * rstd * G.z + B.z);
        pk.w = f2bf((V[c].w - mean) * rstd * G.w + B.w);
        *reinterpret_cast<ushort4*>(&orow[c * 256 + lane * 4]) = pk;
    }
}

// standalone ln (4 rows per block, 1 wave per row)
__global__ __launch_bounds__(256)
void ln_kernel(const float* __restrict__ x, const float* __restrict__ g,
               const float* __restrict__ b, unsigned short* __restrict__ out)
{
    int wid = threadIdx.x >> 6, lane = threadIdx.x & 63;
    ln_row(x, g, b, out, blockIdx.x * 4 + wid, lane);
}

// ---------------- merged prep: weight convert (7 mats) + ln1 + pos -----------
struct WCD { const float* W; unsigned short* Wt; int Kw, Nw, t0; };
struct WCP { WCD e[7]; };
#define WCONV_BLKS 15456
#define LN1_BLKS   384
#define POS_BLKS   (2 * TT - 1)

__global__ __launch_bounds__(256)
void prep_all(WCP p, const float* __restrict__ x,
              const float* __restrict__ ln1_g, const float* __restrict__ ln1_b,
              unsigned short* __restrict__ xnb, unsigned short* __restrict__ pos)
{
    int bid = blockIdx.x;
    int tid = threadIdx.x;

    if (bid < WCONV_BLKS) {
        __shared__ float t[32][33];
        int i = 0;
#pragma unroll
        for (int j = 1; j < 7; j++) if (bid >= p.e[j].t0) i = j;
        const float* W = p.e[i].W;
        unsigned short* Wt = p.e[i].Wt;
        int Kw = p.e[i].Kw, Nw = p.e[i].Nw;
        int local = bid - p.e[i].t0;
        int tpx = Nw >> 5;
        int n0 = (local % tpx) * 32, k0 = (local / tpx) * 32;

        int r = tid >> 3, c4 = (tid & 7) * 4;
        float4 v = *reinterpret_cast<const float4*>(&W[(size_t)(k0 + r) * Nw + n0 + c4]);
        t[r][c4 + 0] = v.x; t[r][c4 + 1] = v.y; t[r][c4 + 2] = v.z; t[r][c4 + 3] = v.w;
        __syncthreads();
        ushort4 pk;
        pk.x = f2bf(t[c4 + 0][r]);
        pk.y = f2bf(t[c4 + 1][r]);
        pk.z = f2bf(t[c4 + 2][r]);
        pk.w = f2bf(t[c4 + 3][r]);
        *reinterpret_cast<ushort4*>(&Wt[(size_t)(n0 + r) * Kw + k0 + c4]) = pk;
        return;
    }

    if (bid < WCONV_BLKS + LN1_BLKS) {
        int grp = bid - WCONV_BLKS;
        int wid = tid >> 6, lane = tid & 63;
        ln_row(x, ln1_g, ln1_b, xnb, grp * 4 + wid, lane);
        return;
    }

    // positional features, one l per block
    {
        int l = bid - (WCONV_BLKS + LN1_BLKS);
        float pp = (float)(l - (TT - 1));
        float ap = fabsf(pp);
        float sgn = (pp > 0.f) ? 1.f : ((pp < 0.f) ? -1.f : 0.f);

        __shared__ float gp[32];
        __shared__ float gmax_s;
        if (tid < 32) {
            int j = tid;
            double conc = 4.0 * (double)(j + 1) * (double)(j + 1);
            double rate = (double)(j + 1) / 12.0;
            double log_norm = lgamma(conc) - conc * log(rate);
            double prob;
            if (ap == 0.f) prob = 1e-8;
            else prob = exp((conc - 1.0) * log((double)ap) - rate * (double)ap - log_norm) + 1e-8;
            gp[j] = (float)prob;
        }
        __syncthreads();
        if (tid == 0) {
            float m = gp[0];
            for (int j = 1; j < 32; j++) m = fmaxf(m, gp[j]);
            gmax_s = m;
        }
        __syncthreads();
        if (tid < 96) {
            int cls = tid / 32, j = tid % 32;
            float val;
            if (cls == 0) {
                double step = (10.584962500721156 - 3.0) / 31.0;
                double hl = exp2(3.0 + j * step);
                val = (float)exp(-(double)ap * 0.6931471805599453 / hl);
            } else if (cls == 1) {
                float width = exp2f((float)(j + 1)) - 1.f;
                val = (width > ap) ? 1.f : 0.f;
            } else {
                val = gp[j] / gmax_s;
            }
            pos[(size_t)l * FD + tid] = f2bf(val);
            pos[(size_t)l * FD + 96 + tid] = f2bf(sgn * val);
        }
    }
}

// ---------------- bf16 MFMA GEMM core, TMxTN tile, 4 waves ----------------
// 2-deep double buffer + counted vmcnt. Wave tile = (TM/2)x(TN/2).
// xm: 2 or 4 -> 2D XCD chunking; 0 -> linear XCD swizzle.
// mode 0: f32 out  mode 1: bf16 out  mode 4: fused qkv epilogue
// head_ndiv!=0: A += (n0/head_ndiv)*sA
template<int TM, int TN>
__device__ void gemm_core(const unsigned short* __restrict__ A,
                          const unsigned short* __restrict__ Bt,
                          void* __restrict__ Cv, unsigned short* __restrict__ C2,
                          unsigned short* __restrict__ C3,
                          int M, int N, int K, int lda, int ldb, int ldc,
                          long sA, long sB, long sC,
                          float alpha, const float* __restrict__ bias,
                          const float* __restrict__ bias2,
                          const float* __restrict__ resid,
                          int mode, int relu, int head_ndiv, int xm,
                          int gx, int gy, int d, int bz)
{
    constexpr int WM = TM / 2, WN = TN / 2;
    constexpr int MF = WM / 16, NF = WN / 16;
    constexpr int LPT = TM / 32 + TN / 32;       // per-thread loads per K-tile
    __shared__ unsigned short lA[2][TM * 64];
    __shared__ unsigned short lB[2][TN * 64];

    int tid = threadIdx.x;
    int w = tid >> 6, l = tid & 63;

    int bx, by;
    if (xm) {
        int xn = 8 / xm;
        int cm = gy / xm, cn = gx / xn;
        int xcd = d & 7, local = d >> 3;
        int bxl = local / cm, byl = local % cm;
        by = (xcd / xn) * cm + byl;
        bx = (xcd % xn) * cn + bxl;
    } else {
        int nwg = gx * gy;
        int work = d;
        if ((nwg & 7) == 0) work = (d & 7) * (nwg >> 3) + (d >> 3);
        bx = work % gx;
        by = work / gx;
    }

    int n0 = bx * TN;
    int m0 = by * TM;
    if (head_ndiv) {
        A += (size_t)(n0 / head_ndiv) * sA;
    } else {
        A  += (size_t)bz * sA;
        Bt += (size_t)bz * sB;
    }
    int R0 = (w & 1) * WM, C0 = (w >> 1) * WN;
    int lrow = l >> 3;
    int lsw = ((l & 7) ^ lrow) << 3;       // swizzled source chunk (elements)
    int l15 = l & 15, lg = l >> 4;

    f32x4 acc[MF][NF] = {};

    const int NSTEP = K >> 6;

    auto STAGE = [&](int t, int buf) {
        int k0 = t << 6;
#pragma unroll
        for (int q = 0; q < TM / 32; q++) {
            int r0 = w * (TM / 4) + q * 8;
            gload16(A + (size_t)(m0 + r0 + lrow) * lda + k0 + lsw, &lA[buf][r0 * 64]);
        }
#pragma unroll
        for (int q = 0; q < TN / 32; q++) {
            int r0 = w * (TN / 4) + q * 8;
            gload16(Bt + (size_t)(n0 + r0 + lrow) * ldb + k0 + lsw, &lB[buf][r0 * 64]);
        }
    };

    STAGE(0, 0);

    int cur = 0;
    for (int t = 0; t < NSTEP; ++t) {
        if (t + 1 < NSTEP) {
            STAGE(t + 1, cur ^ 1);     // buffer freed by barrier at end of t-1
            vmwait<LPT>();             // tile t complete; t+1 stays in flight
        } else {
            vmwait<0>();
        }
        __builtin_amdgcn_s_barrier();
        __builtin_amdgcn_sched_barrier(0);

#pragma unroll
        for (int kk = 0; kk < 2; kk++) {
            int ch = kk * 4 + lg;
            bf16x8 av[MF], bv[NF];
#pragma unroll
            for (int m = 0; m < MF; m++) {
                int row = R0 + m * 16 + l15;
                av[m] = *(const bf16x8*)&lA[cur][row * 64 + swzo(row, ch)];
            }
#pragma unroll
            for (int n = 0; n < NF; n++) {
                int row = C0 + n * 16 + l15;
                bv[n] = *(const bf16x8*)&lB[cur][row * 64 + swzo(row, ch)];
            }
#pragma unroll
            for (int m = 0; m < MF; m++)
#pragma unroll
                for (int n = 0; n < NF; n++)
                    acc[m][n] = __builtin_amdgcn_mfma_f32_16x16x32_bf16(av[m], bv[n], acc[m][n], 0, 0, 0);
        }
        __builtin_amdgcn_s_barrier();  // all waves done reading buf cur
        cur ^= 1;
    }

    int rb = m0 + R0 + lg * 4;
    int cb = n0 + C0 + l15;

    if (mode == 4) {
        unsigned short* qw = (unsigned short*)Cv;
#pragma unroll
        for (int m = 0; m < MF; m++) {
            int rowb = rb + m * 16;
#pragma unroll
            for (int n = 0; n < NF; n++) {
                int col = cb + n * 16;
                if (col < 512) {
#pragma unroll
                    for (int reg = 0; reg < 4; reg++) {
                        int row = rowb + reg;
                        float v = alpha * acc[m][n][reg];
                        qw[(size_t)row * 512 + col] = f2bf(v + bias[col]);
                        C2[(size_t)row * 512 + col] = f2bf(v + bias2[col]);
                    }
                } else if (col < 1024) {
                    unsigned short* kb = C3;
#pragma unroll
                    for (int reg = 0; reg < 4; reg++)
                        kb[(size_t)(rowb + reg) * 512 + col - 512] = f2bf(acc[m][n][reg]);
                } else {
                    unsigned short* vT = (unsigned short*)(void*)(C3 + (size_t)1536 * 512);
                    int vc = col - 1024;
                    ushort4 pk;
                    pk.x = f2bf(acc[m][n][0]);
                    pk.y = f2bf(acc[m][n][1]);
                    pk.z = f2bf(acc[m][n][2]);
                    pk.w = f2bf(acc[m][n][3]);
                    *reinterpret_cast<ushort4*>(&vT[(size_t)vc * 1536 + rowb]) = pk;
                }
            }
        }
        return;
    }

#pragma unroll
    for (int m = 0; m < MF; m++) {
#pragma unroll
        for (int n = 0; n < NF; n++) {
            int col = cb + n * 16;
            if (col >= N) continue;
            float bs = bias ? bias[col] : 0.f;
#pragma unroll
            for (int reg = 0; reg < 4; reg++) {
                int row = rb + m * 16 + reg;
                if (row >= M) continue;
                float v = alpha * acc[m][n][reg] + bs;
                if (resid) v += resid[(size_t)row * ldc + col];
                if (relu)  v = fmaxf(v, 0.f);
                if (mode == 1) {
                    unsigned short* C = (unsigned short*)Cv + (size_t)bz * sC;
                    C[(size_t)row * ldc + col] = f2bf(v);
                } else {
                    float* C = (float*)Cv + (size_t)bz * sC;
                    C[(size_t)row * ldc + col] = v;
                }
            }
        }
    }
}

template<int TM, int TN>
__global__ __launch_bounds__(256)
void gemm_bf16(const unsigned short* __restrict__ A,
               const unsigned short* __restrict__ Bt,
               void* __restrict__ Cv, unsigned short* __restrict__ C2,
               unsigned short* __restrict__ C3,
               int M, int N, int K, int lda, int ldb, int ldc,
               long sA, long sB, long sC,
               float alpha, const float* __restrict__ bias,
               const float* __restrict__ bias2,
               const float* __restrict__ resid,
               int mode, int relu, int head_ndiv, int xm)
{
    int d = blockIdx.y * gridDim.x + blockIdx.x;
    gemm_core<TM, TN>(A, Bt, Cv, C2, C3, M, N, K, lda, ldb, ldc, sA, sB, sC,
                      alpha, bias, bias2, resid, mode, relu, head_ndiv, xm,
                      gridDim.x, gridDim.y, d, blockIdx.z);
}

// two independent <64,128> GEMMs in one launch (block-range dispatch)
struct GP {
    const unsigned short *A, *Bt;
    void* Cv; unsigned short *C2, *C3;
    int M, N, K, lda, ldb, ldc;
    long sA, sB, sC;
    float alpha;
    const float *bias, *bias2, *resid;
    int mode, relu, head_ndiv, xm, gx, gy;
};

__global__ __launch_bounds__(256)
void gemm_dual128(GP a, GP b, int nblk0)
{
    int bid = blockIdx.x;
    if (bid < nblk0) {
        gemm_core<64, 128>(a.A, a.Bt, a.Cv, a.C2, a.C3, a.M, a.N, a.K,
                           a.lda, a.ldb, a.ldc, a.sA, a.sB, a.sC, a.alpha,
                           a.bias, a.bias2, a.resid, a.mode, a.relu,
                           a.head_ndiv, a.xm, a.gx, a.gy, bid, 0);
    } else {
        gemm_core<64, 128>(b.A, b.Bt, b.Cv, b.C2, b.C3, b.M, b.N, b.K,
                           b.lda, b.ldb, b.ldc, b.sA, b.sB, b.sC, b.alpha,
                           b.bias, b.bias2, b.resid, b.mode, b.relu,
                           b.head_ndiv, b.xm, b.gx, b.gy, bid - nblk0, 0);
    }
}

// ---------------- MFMA logits: content + shifted rel -> bf16 [8,T,T] ----------
// 40 KB LDS (shift buffer aliased over lQw/lQr as bf16) -> 4 blocks/CU
__global__ __launch_bounds__(256)
void logits_mfma(const unsigned short* __restrict__ qw,
                 const unsigned short* __restrict__ qr,
                 const unsigned short* __restrict__ kmat,
                 const unsigned short* __restrict__ rk,
                 unsigned short* __restrict__ out)
{
    __shared__ unsigned short pool[3 * 64 * 64 + 128 * 64];
    unsigned short* lQw = pool;
    unsigned short* lQr = pool + 64 * 64;
    unsigned short* lK  = pool + 2 * 64 * 64;
    unsigned short* lR  = pool + 3 * 64 * 64;
    unsigned short* lC2 = pool;              // alias lQw+lQr: [64][128] bf16

    int j0 = blockIdx.x * 64;
    int i0 = blockIdx.y * 64;
    int h  = blockIdx.z;
    int tid = threadIdx.x;
    int w = tid >> 6, l = tid & 63;
    int lrow = l >> 3;
    int lsw = ((l & 7) ^ lrow) << 3;
    int l15 = l & 15, lg = l >> 4;
    int obase = j0 - i0 + 1472;

#pragma unroll
    for (int q = 0; q < 2; q++) {
        int r0 = w * 16 + q * 8;
        gload16(qw   + (size_t)(i0 + r0 + lrow) * (NH * KD) + h * KD + lsw, &lQw[r0 * 64]);
        gload16(qr   + (size_t)(i0 + r0 + lrow) * (NH * KD) + h * KD + lsw, &lQr[r0 * 64]);
        gload16(kmat + (size_t)(j0 + r0 + lrow) * (NH * KD) + h * KD + lsw, &lK [r0 * 64]);
    }
#pragma unroll
    for (int q = 0; q < 4; q++) {
        int r0 = w * 32 + q * 8;
        gload16(rk + (size_t)(obase + r0 + lrow) * (NH * KD) + h * KD + lsw, &lR[r0 * 64]);
    }
    __syncthreads();

    f32x4 acc1[4] = {};
    f32x4 acc2[8] = {};
#pragma unroll
    for (int kk = 0; kk < 2; kk++) {
        int ch = kk * 4 + lg;
        int qrow = 16 * w + l15;
        bf16x8 av  = *(const bf16x8*)&lQw[qrow * 64 + swzo(qrow, ch)];
        bf16x8 arv = *(const bf16x8*)&lQr[qrow * 64 + swzo(qrow, ch)];
#pragma unroll
        for (int n = 0; n < 4; n++) {
            int row = n * 16 + l15;
            bf16x8 bv = *(const bf16x8*)&lK[row * 64 + swzo(row, ch)];
            acc1[n] = __builtin_amdgcn_mfma_f32_16x16x32_bf16(av, bv, acc1[n], 0, 0, 0);
        }
#pragma unroll
        for (int n = 0; n < 8; n++) {
            int row = n * 16 + l15;
            bf16x8 rv = *(const bf16x8*)&lR[row * 64 + swzo(row, ch)];
            acc2[n] = __builtin_amdgcn_mfma_f32_16x16x32_bf16(arv, rv, acc2[n], 0, 0, 0);
        }
    }
    __syncthreads();          // all reads of lQw/lQr done before aliased writes

#pragma unroll
    for (int n = 0; n < 8; n++)
#pragma unroll
        for (int reg = 0; reg < 4; reg++)
            lC2[(16 * w + lg * 4 + reg) * 128 + n * 16 + l15] = f2bf(acc2[n][reg]);
    __syncthreads();

#pragma unroll
    for (int n = 0; n < 4; n++) {
#pragma unroll
        for (int reg = 0; reg < 4; reg++) {
            int u = 16 * w + lg * 4 + reg;
            int v = n * 16 + l15;
            float val = acc1[n][reg] + bf2f(lC2[u * 128 + 63 + v - u]);
            out[((size_t)h * TT + i0 + u) * TT + j0 + v] = f2bf(val);
        }
    }
}

// ---------------- Row softmax bf16 in-place, 1 wave per row ----------------
__global__ __launch_bounds__(256)
void softmax_bf16(unsigned short* __restrict__ P)
{
    int wid = threadIdx.x >> 6, lane = threadIdx.x & 63;
    size_t r = (size_t)blockIdx.x * 4 + wid;
    unsigned* row = (unsigned*)(P + r * TT);

    uint4 U[3];
    float v[24];
    float m = -1e30f;
#pragma unroll
    for (int c = 0; c < 3; c++) {
        U[c] = *reinterpret_cast<const uint4*>(&row[c * 256 + lane * 4]);
        const unsigned* pd = (const unsigned*)&U[c];
#pragma unroll
        for (int d = 0; d < 4; d++) {
            float lo = bf2f((unsigned short)(pd[d] & 0xFFFF));
            float hi = bf2f((unsigned short)(pd[d] >> 16));
            v[c * 8 + 2 * d]     = lo;
            v[c * 8 + 2 * d + 1] = hi;
            m = fmaxf(m, fmaxf(lo, hi));
        }
    }
#pragma unroll
    for (int off = 32; off; off >>= 1) m = fmaxf(m, __shfl_xor(m, off));
    float s = 0.f;
#pragma unroll
    for (int i = 0; i < 24; i++) { v[i] = __expf(v[i] - m); s += v[i]; }
#pragma unroll
    for (int off = 32; off; off >>= 1) s += __shfl_xor(s, off);
    float inv = 1.f / s;
#pragma unroll
    for (int c = 0; c < 3; c++) {
        unsigned* pd = (unsigned*)&U[c];
#pragma unroll
        for (int d = 0; d < 4; d++)
            pd[d] = (unsigned)f2bf(v[c * 8 + 2 * d] * inv)
                  | ((unsigned)f2bf(v[c * 8 + 2 * d + 1] * inv) << 16);
        *reinterpret_cast<uint4*>(&row[c * 256 + lane * 4]) = U[c];
    }
}

// ---------------- launcher ----------------
extern "C" void kernel_launch(void* const* d_in, const int* in_sizes, int n_in,
                              void* d_out, int out_size, void* d_ws, size_t ws_size,
                              hipStream_t stream)
{
    const float* x     = (const float*)d_in[0];
    const float* ln1_g = (const float*)d_in[1];
    const float* ln1_b = (const float*)d_in[2];
    const float* ln2_g = (const float*)d_in[3];
    const float* ln2_b = (const float*)d_in[4];
    const float* Wq    = (const float*)d_in[5];
    const float* Wk    = (const float*)d_in[6];
    const float* Wv    = (const float*)d_in[7];
    const float* Wr    = (const float*)d_in[8];
    const float* Wo    = (const float*)d_in[9];
    const float* bo    = (const float*)d_in[10];
    const float* rwb   = (const float*)d_in[11];
    const float* rrb   = (const float*)d_in[12];
    const float* W1    = (const float*)d_in[13];
    const float* b1    = (const float*)d_in[14];
    const float* W2    = (const float*)d_in[15];
    const float* b2    = (const float*)d_in[16];
    float* out = (float*)d_out;

    char* w8 = (char*)d_ws;
    unsigned short* xnb  = (unsigned short*)(w8 + 0);         // [1536][1536]
    unsigned short* qwb  = (unsigned short*)(w8 + 4718592);   // [1536][512]
    unsigned short* qrb  = (unsigned short*)(w8 + 6291456);   // [1536][512]
    unsigned short* kbb  = (unsigned short*)(w8 + 7864320);   // [1536][512]
    unsigned short* vTb  = (unsigned short*)(w8 + 9437184);   // [1536][1536] (= kbb + 1536*512)
    unsigned short* posb = (unsigned short*)(w8 + 14155776);  // [3072][192]
    unsigned short* rkb  = (unsigned short*)(w8 + 15335424);  // [3072][512]
    unsigned short* Pb   = (unsigned short*)(w8 + 18481152);  // [8][1536][1536]
    unsigned short* ob   = (unsigned short*)(w8 + 56229888);  // [1536][1536]
    float*          yb   = (float*)        (w8 + 60948480);   // [1536][1536] f32
    unsigned short* WqkvT= (unsigned short*)(w8 + 70385664);  // [2560][1536]
    unsigned short* WrT  = (unsigned short*)(w8 + 78249984);  // [512][192]
    unsigned short* WoT  = (unsigned short*)(w8 + 78446592);  // [1536][1536]
    unsigned short* W1T  = (unsigned short*)(w8 + 83165184);  // [3072][1536]
    unsigned short* W2T  = (unsigned short*)(w8 + 92602368);  // [1536][3072]
    unsigned short* h1b  = Pb;    // reuse after AV
    unsigned short* ynb  = xnb;   // reuse after QKV

    // merged prep: weight conversions (bf16, transposed) + ln1 + pos
    WCP wp;
    wp.e[0] = { Wq, WqkvT,                       1536, 512,      0 };
    wp.e[1] = { Wk, WqkvT + (size_t)512 * 1536,  1536, 512,    768 };
    wp.e[2] = { Wv, WqkvT + (size_t)1024 * 1536, 1536, 1536,  1536 };
    wp.e[3] = { Wr, WrT,                          192, 512,   3840 };
    wp.e[4] = { Wo, WoT,                         1536, 1536,  3936 };
    wp.e[5] = { W1, W1T,                         1536, 3072,  6240 };
    wp.e[6] = { W2, W2T,                         3072, 1536, 10848 };
    prep_all<<<WCONV_BLKS + LN1_BLKS + POS_BLKS, 256, 0, stream>>>(
        wp, x, ln1_g, ln1_b, xnb, posb);

    // merged launch: fused qkv (480 blocks, 2D XCD chunks) + rk (192 blocks)
    GP ga = { xnb, WqkvT, qwb, qrb, kbb,
              1536, 2560, 1536, 1536, 1536, 0,
              0, 0, 0,
              0.125f, rwb, rrb, nullptr,
              4, 0, 0, 2, 20, 24 };
    GP gb = { posb, WrT, rkb, nullptr, nullptr,
              3071, 512, 192, 192, 192, 512,
              0, 0, 0,
              1.f, nullptr, nullptr, nullptr,
              1, 0, 0, 2, 4, 48 };
    gemm_dual128<<<672, 256, 0, stream>>>(ga, gb, 480);

    // logits + softmax (in place, bf16)
    logits_mfma<<<dim3(24, 24, 8), 256, 0, stream>>>(qwb, qrb, kbb, rkb, Pb);
    softmax_bf16<<<NH * TT / 4, 256, 0, stream>>>(Pb);

    // o = P @ V : 64x64 tile (576 blocks), head from n0/192
    gemm_bf16<64, 64><<<dim3(24, 24, 1), 256, 0, stream>>>(Pb, vTb, ob, nullptr, nullptr,
        1536, 1536, 1536, 1536, 1536, 1536, (long)TT * TT, 0, 0,
        1.f, nullptr, nullptr, nullptr, 1, 0, VD, 2);

    // y = o @ Wo + bo + x   (f32) : 64x64 tile (576 blocks ~2.25/CU)
    gemm_bf16<64, 64><<<dim3(24, 24, 1), 256, 0, stream>>>(ob, WoT, yb, nullptr, nullptr,
        1536, 1536, 1536, 1536, 1536, 1536, 0, 0, 0,
        1.f, bo, nullptr, x, 0, 0, 0, 2);

    ln_kernel<<<TT / 4, 256, 0, stream>>>(yb, ln2_g, ln2_b, ynb);

    // h1 = relu(yn @ W1 + b1) bf16 : 64x128 tile (576 blocks)
    gemm_bf16<64, 128><<<dim3(24, 24, 1), 256, 0, stream>>>(ynb, W1T, h1b, nullptr, nullptr,
        1536, 3072, 1536, 1536, 1536, 3072, 0, 0, 0,
        1.f, b1, nullptr, nullptr, 1, 1, 0, 2);

    // out = y + h1 @ W2 + b2   (f32) : 64x64 tile (576 blocks), XM=4 for L2 fit
    gemm_bf16<64, 64><<<dim3(24, 24, 1), 256, 0, stream>>>(h1b, W2T, out, nullptr, nullptr,
        1536, 1536, 3072, 3072, 3072, 1536, 0, 0, 0,
        1.f, b2, nullptr, yb, 0, 0, 0, 4);
}